// Round 10
// baseline (99.889 us; speedup 1.0000x reference)
//
#include <hip/hip_runtime.h>

// DenseWarp: out[b,c,y,x] = bilinear(frame[b,c], qy, qx)
//   qy = clip(y - flow[b,0,y,x], 0, H-1), qx = clip(x - flow[b,1,y,x], 0, W-1)
// fp32 in/out. B=4, C=4, H=1080, W=1920.
//
// R10: best-of recombination.
//  - prepass: EXACT R5 shape (2 px/thread, regular f32x2 frame loads, h8
//    store) — R8/R9's NT-quad prepass regressed ~5us, reverted.
//  - gather: 4 independent lane-adjacent pixels per thread (4 chunks of
//    256 px) -> 4 concurrent flow->gather->store chains per wave for
//    latency hiding; NT flow loads (read-once, keep LLC for ws).
//  - bijective XCD swizzle everywhere (gather grid 8100 % 8 != 0).

#define BB 4
#define CC 4
#define HH 1080
#define WW 1920
#define HW (HH * WW)
#define NPX (BB * HH * WW)              // 8,294,400 pixels (b,y,x)
#define WS_BYTES ((size_t)NPX * CC * 2) // 66,355,200 B
#define NBLK_P (NPX / 2 / 256)          // 16,200 (prepass: 2 px/thread)
#define NBLK_G (NPX / 4 / 256)          // 8,100  (gather: 4 px/thread)
#define NBLK_F (NPX / 256)              // 32,400 (fallback)

typedef _Float16 h8 __attribute__((ext_vector_type(8), aligned(8)));
typedef float f32x4 __attribute__((ext_vector_type(4), aligned(16)));
typedef float f32x2 __attribute__((ext_vector_type(2), aligned(4)));

// m204 bijective XCD swizzle — valid for ANY nblk.
__device__ __forceinline__ int xcd_swizzle(int n, int nblk)
{
    const int q   = nblk >> 3;
    const int r   = nblk & 7;
    const int xcd = n & 7;
    const int loc = n >> 3;
    const int base = (xcd < r) ? xcd * (q + 1) : r * (q + 1) + (xcd - r) * q;
    return base + loc;
}

__global__ __launch_bounds__(256) void nhwc_fp16_prepass(
    const float* __restrict__ frame,
    _Float16* __restrict__ ws)
{
    const int blk = xcd_swizzle(blockIdx.x, NBLK_P);
    const int p   = (blk * 256 + threadIdx.x) * 2;   // first of 2 pixels
    const int x = p % WW;
    const int t = p / WW;
    const int y = t % HH;
    const int b = t / HH;

    const size_t off = (size_t)(b * CC) * HW + (size_t)y * WW + x;
    h8 o;
#pragma unroll
    for (int c = 0; c < CC; ++c) {
        const f32x2 v = *reinterpret_cast<const f32x2*>(frame + off + (size_t)c * HW);
        o[c]     = (_Float16)v.x;
        o[c + 4] = (_Float16)v.y;
    }
    // regular store: ws should be LLC-resident for the gather pass
    *reinterpret_cast<h8*>(ws + (size_t)p * 4) = o;
}

__global__ __launch_bounds__(256) void dense_warp_gather(
    const _Float16* __restrict__ ws,
    const float* __restrict__ flow,
    float* __restrict__ out)
{
    const int blk  = xcd_swizzle(blockIdx.x, NBLK_G);
    const int base = blk * 1024;   // block owns 1024 px in four 256-px chunks

    // four independent pixels per thread, each in a lane-adjacent chunk
#pragma unroll
    for (int k = 0; k < 4; ++k) {
        const int p = base + k * 256 + threadIdx.x;
        const int x = p % WW;
        const int t = p / WW;
        const int y = t % HH;
        const int b = t / HH;

        const size_t rowoff = (size_t)y * WW + x;
        const float* __restrict__ flowy = flow + (size_t)(b * 2) * HW;
        const float* __restrict__ flowx = flowy + HW;
        const _Float16* __restrict__ wsb = ws + (size_t)b * HW * 4;
        float* __restrict__ outb = out + (size_t)(b * CC) * HW;

        // NT: flow is read exactly once; don't evict LLC-resident ws
        const float fy = __builtin_nontemporal_load(flowy + rowoff);
        const float fx = __builtin_nontemporal_load(flowx + rowoff);

        // same op order as reference
        const float qy  = fminf(fmaxf((float)y - fy, 0.0f), (float)(HH - 1));
        const float qx  = fminf(fmaxf((float)x - fx, 0.0f), (float)(WW - 1));
        const float y0f = floorf(qy);
        const float x0f = floorf(qx);
        const float wy  = qy - y0f;
        float       wx  = qx - x0f;
        const int y0 = (int)y0f;
        const int x0 = (int)x0f;
        const int y1 = min(y0 + 1, HH - 1);

        // right-edge: x0==W-1 -> wx==0; load pair at W-2 with wx=1 (identical)
        const bool edge = (x0 > WW - 2);
        const int  xb   = edge ? (WW - 2) : x0;
        if (edge) wx = 1.0f;

        // one 16B load per row covers 4 channels x 2 pixels (NHWC fp16)
        const h8 tp = *reinterpret_cast<const h8*>(wsb + ((size_t)y0 * WW + xb) * 4);
        const h8 bt = *reinterpret_cast<const h8*>(wsb + ((size_t)y1 * WW + xb) * 4);

        const float omwx = 1.0f - wx;
        const float omwy = 1.0f - wy;

#pragma unroll
        for (int c = 0; c < CC; ++c) {
            const float tl = (float)tp[c];
            const float tr = (float)tp[c + 4];
            const float bl = (float)bt[c];
            const float br = (float)bt[c + 4];
            const float top = tl * omwx + tr * wx;
            const float bot = bl * omwx + br * wx;
            const float v   = top * omwy + bot * wy;
            __builtin_nontemporal_store(v, outb + (size_t)c * HW + rowoff);
        }
    }
}

// exact-fp32 single-pass fallback if ws_size is insufficient (R3 kernel)
__global__ __launch_bounds__(256) void dense_warp_fallback(
    const float* __restrict__ frame,
    const float* __restrict__ flow,
    float* __restrict__ out)
{
    const int blk = xcd_swizzle(blockIdx.x, NBLK_F);
    const int p   = blk * 256 + threadIdx.x;
    const int x = p % WW;
    const int t = p / WW;
    const int y = t % HH;
    const int b = t / HH;

    const size_t rowoff = (size_t)y * WW + x;
    const float fy = flow[(size_t)(b * 2 + 0) * HW + rowoff];
    const float fx = flow[(size_t)(b * 2 + 1) * HW + rowoff];

    const float qy  = fminf(fmaxf((float)y - fy, 0.0f), (float)(HH - 1));
    const float qx  = fminf(fmaxf((float)x - fx, 0.0f), (float)(WW - 1));
    const float y0f = floorf(qy);
    const float x0f = floorf(qx);
    const float wy  = qy - y0f;
    float       wx  = qx - x0f;
    const int y0 = (int)y0f;
    const int x0 = (int)x0f;
    const int y1 = min(y0 + 1, HH - 1);
    const bool edge = (x0 > WW - 2);
    const int  xb   = edge ? (WW - 2) : x0;
    if (edge) wx = 1.0f;

    const int i0 = y0 * WW + xb;
    const int i1 = y1 * WW + xb;
    const float omwx = 1.0f - wx;
    const float omwy = 1.0f - wy;

#pragma unroll
    for (int c = 0; c < CC; ++c) {
        const float* fp = frame + (size_t)(b * CC + c) * HW;
        const f32x2 t2 = *reinterpret_cast<const f32x2*>(fp + i0);
        const f32x2 b2 = *reinterpret_cast<const f32x2*>(fp + i1);
        const float top = t2.x * omwx + t2.y * wx;
        const float bot = b2.x * omwx + b2.y * wx;
        const float v   = top * omwy + bot * wy;
        __builtin_nontemporal_store(v, out + (size_t)(b * CC + c) * HW + rowoff);
    }
}

extern "C" void kernel_launch(void* const* d_in, const int* in_sizes, int n_in,
                              void* d_out, int out_size, void* d_ws, size_t ws_size,
                              hipStream_t stream)
{
    const float* frame = (const float*)d_in[0];
    const float* flow  = (const float*)d_in[1];
    float* out = (float*)d_out;

    if (ws_size >= WS_BYTES && d_ws != nullptr) {
        _Float16* ws = (_Float16*)d_ws;
        nhwc_fp16_prepass<<<NBLK_P, 256, 0, stream>>>(frame, ws);
        dense_warp_gather<<<NBLK_G, 256, 0, stream>>>(ws, flow, out);
    } else {
        dense_warp_fallback<<<NBLK_F, 256, 0, stream>>>(frame, flow, out);
    }
}

// Round 11
// 70.498 us; speedup vs baseline: 1.4169x; 1.4169x over previous
//
#include <hip/hip_runtime.h>

// DenseWarp: out[b,c,y,x] = bilinear(frame[b,c], qy, qx)
//   qy = clip(y - flow[b,0,y,x], 0, H-1), qx = clip(x - flow[b,1,y,x], 0, W-1)
// fp32 in/out. B=4, C=4, H=1080, W=1920.
//
// R11 = R5 restored verbatim (best measured: 69.9 us harness), with the
// bijective XCD swizzle helper (identical mapping to R5's simple swizzle
// since both grids are divisible by 8; kept for safety per ERRATA #11).
//   pass 1: NCHW -> NHWC fp16 prepass into d_ws, 2 px/thread, regular
//           f32x2 frame loads (NT/quad variants measurably regressed).
//   pass 2: gather, 1 px/thread, lane-adjacent (max TLP, 12 VGPR):
//           2 scalar flow loads, 2 h8 divergent gathers from LLC-resident
//           ws, 4 NT plane stores.
// Failed variants (do not retry): LDS staging (R4 +84us), 2D L1 tiling
// (R6 +1.3), adjacent-quad (R8 +11.5), chunked-2px ILP (R9 +4.3),
// chunked-4px + NT flow (R10 +30).

#define BB 4
#define CC 4
#define HH 1080
#define WW 1920
#define HW (HH * WW)
#define NPX (BB * HH * WW)              // 8,294,400 pixels (b,y,x)
#define WS_BYTES ((size_t)NPX * CC * 2) // 66,355,200 B
#define NBLK_P (NPX / 2 / 256)          // 16,200 (prepass: 2 px/thread)
#define NBLK_G (NPX / 256)              // 32,400 (gather: 1 px/thread)

typedef _Float16 h8 __attribute__((ext_vector_type(8), aligned(8)));
typedef float f32x2 __attribute__((ext_vector_type(2), aligned(4)));

// m204 bijective XCD swizzle — valid for ANY nblk (== simple swizzle when
// nblk % 8 == 0, which holds for both grids here).
__device__ __forceinline__ int xcd_swizzle(int n, int nblk)
{
    const int q   = nblk >> 3;
    const int r   = nblk & 7;
    const int xcd = n & 7;
    const int loc = n >> 3;
    const int base = (xcd < r) ? xcd * (q + 1) : r * (q + 1) + (xcd - r) * q;
    return base + loc;
}

__global__ __launch_bounds__(256) void nhwc_fp16_prepass(
    const float* __restrict__ frame,
    _Float16* __restrict__ ws)
{
    const int blk = xcd_swizzle(blockIdx.x, NBLK_P);
    const int p   = (blk * 256 + threadIdx.x) * 2;   // first of 2 pixels
    const int x = p % WW;
    const int t = p / WW;
    const int y = t % HH;
    const int b = t / HH;

    const size_t off = (size_t)(b * CC) * HW + (size_t)y * WW + x;
    h8 o;
#pragma unroll
    for (int c = 0; c < CC; ++c) {
        const f32x2 v = *reinterpret_cast<const f32x2*>(frame + off + (size_t)c * HW);
        o[c]     = (_Float16)v.x;
        o[c + 4] = (_Float16)v.y;
    }
    // regular store: ws should be LLC-resident for the gather pass
    *reinterpret_cast<h8*>(ws + (size_t)p * 4) = o;
}

__global__ __launch_bounds__(256) void dense_warp_gather(
    const _Float16* __restrict__ ws,
    const float* __restrict__ flow,
    float* __restrict__ out)
{
    const int blk = xcd_swizzle(blockIdx.x, NBLK_G);
    const int p   = blk * 256 + threadIdx.x;
    const int x = p % WW;
    const int t = p / WW;
    const int y = t % HH;
    const int b = t / HH;

    const size_t rowoff = (size_t)y * WW + x;
    const float* __restrict__ flowy = flow + (size_t)(b * 2) * HW;
    const float* __restrict__ flowx = flowy + HW;
    const _Float16* __restrict__ wsb = ws + (size_t)b * HW * 4;
    float* __restrict__ outb = out + (size_t)(b * CC) * HW;

    const float fy = flowy[rowoff];
    const float fx = flowx[rowoff];

    // same op order as reference
    const float qy  = fminf(fmaxf((float)y - fy, 0.0f), (float)(HH - 1));
    const float qx  = fminf(fmaxf((float)x - fx, 0.0f), (float)(WW - 1));
    const float y0f = floorf(qy);
    const float x0f = floorf(qx);
    const float wy  = qy - y0f;
    float       wx  = qx - x0f;
    const int y0 = (int)y0f;
    const int x0 = (int)x0f;
    const int y1 = min(y0 + 1, HH - 1);

    // right-edge: x0==W-1 -> wx==0; load pair at W-2 with wx=1 (identical)
    const bool edge = (x0 > WW - 2);
    const int  xb   = edge ? (WW - 2) : x0;
    if (edge) wx = 1.0f;

    // one 16B load per row covers 4 channels x 2 pixels (NHWC fp16)
    const h8 tp = *reinterpret_cast<const h8*>(wsb + ((size_t)y0 * WW + xb) * 4);
    const h8 bt = *reinterpret_cast<const h8*>(wsb + ((size_t)y1 * WW + xb) * 4);

    const float omwx = 1.0f - wx;
    const float omwy = 1.0f - wy;

#pragma unroll
    for (int c = 0; c < CC; ++c) {
        const float tl = (float)tp[c];
        const float tr = (float)tp[c + 4];
        const float bl = (float)bt[c];
        const float br = (float)bt[c + 4];
        const float top = tl * omwx + tr * wx;
        const float bot = bl * omwx + br * wx;
        const float v   = top * omwy + bot * wy;
        __builtin_nontemporal_store(v, outb + (size_t)c * HW + rowoff);
    }
}

// exact-fp32 single-pass fallback if ws_size is insufficient (R3 kernel)
__global__ __launch_bounds__(256) void dense_warp_fallback(
    const float* __restrict__ frame,
    const float* __restrict__ flow,
    float* __restrict__ out)
{
    const int blk = xcd_swizzle(blockIdx.x, NBLK_G);
    const int p   = blk * 256 + threadIdx.x;
    const int x = p % WW;
    const int t = p / WW;
    const int y = t % HH;
    const int b = t / HH;

    const size_t rowoff = (size_t)y * WW + x;
    const float fy = flow[(size_t)(b * 2 + 0) * HW + rowoff];
    const float fx = flow[(size_t)(b * 2 + 1) * HW + rowoff];

    const float qy  = fminf(fmaxf((float)y - fy, 0.0f), (float)(HH - 1));
    const float qx  = fminf(fmaxf((float)x - fx, 0.0f), (float)(WW - 1));
    const float y0f = floorf(qy);
    const float x0f = floorf(qx);
    const float wy  = qy - y0f;
    float       wx  = qx - x0f;
    const int y0 = (int)y0f;
    const int x0 = (int)x0f;
    const int y1 = min(y0 + 1, HH - 1);
    const bool edge = (x0 > WW - 2);
    const int  xb   = edge ? (WW - 2) : x0;
    if (edge) wx = 1.0f;

    const int i0 = y0 * WW + xb;
    const int i1 = y1 * WW + xb;
    const float omwx = 1.0f - wx;
    const float omwy = 1.0f - wy;

#pragma unroll
    for (int c = 0; c < CC; ++c) {
        const float* fp = frame + (size_t)(b * CC + c) * HW;
        const f32x2 t2 = *reinterpret_cast<const f32x2*>(fp + i0);
        const f32x2 b2 = *reinterpret_cast<const f32x2*>(fp + i1);
        const float top = t2.x * omwx + t2.y * wx;
        const float bot = b2.x * omwx + b2.y * wx;
        const float v   = top * omwy + bot * wy;
        __builtin_nontemporal_store(v, out + (size_t)(b * CC + c) * HW + rowoff);
    }
}

extern "C" void kernel_launch(void* const* d_in, const int* in_sizes, int n_in,
                              void* d_out, int out_size, void* d_ws, size_t ws_size,
                              hipStream_t stream)
{
    const float* frame = (const float*)d_in[0];
    const float* flow  = (const float*)d_in[1];
    float* out = (float*)d_out;

    if (ws_size >= WS_BYTES && d_ws != nullptr) {
        _Float16* ws = (_Float16*)d_ws;
        nhwc_fp16_prepass<<<NBLK_P, 256, 0, stream>>>(frame, ws);
        dense_warp_gather<<<NBLK_G, 256, 0, stream>>>(ws, flow, out);
    } else {
        dense_warp_fallback<<<NBLK_G, 256, 0, stream>>>(frame, flow, out);
    }
}